// Round 10
// baseline (295.099 us; speedup 1.0000x reference)
//
#include <hip/hip_runtime.h>
#include <hip/hip_bf16.h>
#include <stdint.h>

typedef __attribute__((ext_vector_type(8))) short short8;
typedef __attribute__((ext_vector_type(4))) short short4_t;
typedef __attribute__((ext_vector_type(4))) float f32x4;
typedef __attribute__((ext_vector_type(2))) unsigned int u32x2;
typedef __attribute__((ext_vector_type(4))) unsigned int u32x4;

union FragU { u32x4 u; short8 s; };
union Frag2U { u32x2 u; short4_t s; };

__device__ __forceinline__ unsigned short f2bf(float f) {
  union { float f; uint32_t u; } v; v.f = f;
  uint32_t u = v.u;
  return (unsigned short)((u + 0x7FFFu + ((u >> 16) & 1u)) >> 16);
}

__device__ __forceinline__ unsigned pk2(float a, float b) {
  return (unsigned)f2bf(a) | ((unsigned)f2bf(b) << 16);
}

#if defined(__has_builtin)
#if __has_builtin(__builtin_amdgcn_mfma_f32_16x16x16bf16_1k)
#define HAVE_MFMA16_BUILTIN 1
#endif
#if __has_builtin(__builtin_amdgcn_exp2f)
#define HAVE_EXP2_BUILTIN 1
#endif
#endif

__device__ __forceinline__ float fexp2(float x) {
#ifdef HAVE_EXP2_BUILTIN
  return __builtin_amdgcn_exp2f(x);
#else
  return exp2f(x);
#endif
}

__device__ __forceinline__ f32x4 mfma16(u32x2 a, u32x2 b, f32x4 c) {
#ifdef HAVE_MFMA16_BUILTIN
  Frag2U ua, ub;
  ua.u = a; ub.u = b;
  return __builtin_amdgcn_mfma_f32_16x16x16bf16_1k(ua.s, ub.s, c, 0, 0, 0);
#else
  asm volatile("s_nop 1\n\t"
               "v_mfma_f32_16x16x16_bf16 %0, %1, %2, %0\n\t"
               "s_nop 7\n\t"
               "s_nop 7"
               : "+v"(c) : "v"(a), "v"(b));
  return c;
#endif
}

// ---------------- K0: convert W (f32, [n][k] row-major) -> bf16, same layout ----------------
__global__ __launch_bounds__(256) void k_wconv(const float* __restrict__ WQ,
                                               const float* __restrict__ WK,
                                               const float* __restrict__ WV,
                                               unsigned short* __restrict__ Wbf) {
  int mat = blockIdx.x >> 5;
  int i = blockIdx.x & 31;
  const float* W = (mat == 0) ? WQ : ((mat == 1) ? WK : WV);
  int off = i * 2048 + threadIdx.x * 8;
  f32x4 v0 = *(const f32x4*)(W + off), v1 = *(const f32x4*)(W + off + 4);
  u32x4 pk;
  pk.x = pk2(v0.x, v0.y); pk.y = pk2(v0.z, v0.w);
  pk.z = pk2(v1.x, v1.y); pk.w = pk2(v1.z, v1.w);
  *(u32x4*)(Wbf + (size_t)mat * 65536 + off) = pk;
}

// ---------------- K1a: per-column partial sums over 64-row chunks ----------------
__global__ __launch_bounds__(256) void k_stats(const float* __restrict__ x,
                                               float* __restrict__ psum,
                                               float* __restrict__ psq) {
  int t = threadIdx.x;
  int cb = blockIdx.x & 3;
  int ck = blockIdx.x >> 2;
  int c0 = cb * 1024 + t * 4;
  f32x4 s = {0.f, 0.f, 0.f, 0.f}, q = {0.f, 0.f, 0.f, 0.f};
  const float* base = x + (size_t)ck * 64 * 4096 + c0;
#pragma unroll 4
  for (int r = 0; r < 64; ++r) {
    f32x4 v = *(const f32x4*)(base + (size_t)r * 4096);
    s += v;
    q += v * v;
  }
  *(f32x4*)(psum + (size_t)ck * 4096 + c0) = s;
  *(f32x4*)(psq + (size_t)ck * 4096 + c0) = q;
}

// ---------------- K1b: finalize BN -> fused scale/shift coeffs ----------------
__global__ __launch_bounds__(256) void k_finalize(const float* __restrict__ psum,
                                                  const float* __restrict__ psq,
                                                  const float* __restrict__ gamma,
                                                  const float* __restrict__ beta,
                                                  float* __restrict__ An,
                                                  float* __restrict__ Bn) {
  int c = blockIdx.x * 256 + threadIdx.x;
  float s = 0.f, q = 0.f;
  for (int k = 0; k < 64; ++k) {
    s += psum[k * 4096 + c];
    q += psq[k * 4096 + c];
  }
  float mean = s * (1.0f / 4096.0f);
  float var = q * (1.0f / 4096.0f) - mean * mean;
  float a = gamma[c] * rsqrtf(var + 1e-5f);
  An[c] = a;
  Bn[c] = beta[c] - mean * a;
}

// ---------------- K2: fused QKV + attention; one BLOCK = one batch row ----------------
// Phase 1 (per wave): qf for its 4 e-tiles (32 MFMA32) + kf/vf for its 4 K/V chunks
//   (64 MFMA32), published to LDS per-lane (same-lane write/read => layouts unchanged).
// Phase 2 (per wave): stream all 16 chunks from LDS: QK^T -> exp2 -> PV on its e-tiles.
#define KFO 0
#define VFO 8192
__global__ __launch_bounds__(256, 4) void k_fused(
    const float* __restrict__ x, const float* __restrict__ An, const float* __restrict__ Bn,
    const unsigned short* __restrict__ Wbf,
    const float* __restrict__ bQ, const float* __restrict__ bK, const float* __restrict__ bV,
    float* __restrict__ out) {
  __shared__ char lds[16384];
  int t = threadIdx.x;
  int w = t >> 6, ln = t & 63, lr = ln & 15, g = ln >> 4;
  int b = blockIdx.x;
  const float* xrow = x + (size_t)b * 4096;

  f32x4 z4 = {0.f, 0.f, 0.f, 0.f};

  // ---- build af[8]: Xn[p=lr][dd=kk*32+g*8+j] (A-frag for Q/K GEMM, B-frag for V GEMM) ----
  FragU af[8];
#pragma unroll
  for (int kk = 0; kk < 8; ++kk) {
    int c = lr * 256 + kk * 32 + g * 8;
    f32x4 v0 = *(const f32x4*)(xrow + c), v1 = *(const f32x4*)(xrow + c + 4);
    f32x4 a0 = *(const f32x4*)(An + c), a1 = *(const f32x4*)(An + c + 4);
    f32x4 b0 = *(const f32x4*)(Bn + c), b1 = *(const f32x4*)(Bn + c + 4);
    f32x4 n0 = v0 * a0 + b0, n1 = v1 * a1 + b1;
    af[kk].u.x = pk2(n0.x, n0.y);
    af[kk].u.y = pk2(n0.z, n0.w);
    af[kk].u.z = pk2(n1.x, n1.y);
    af[kk].u.w = pk2(n1.z, n1.w);
  }

  const char* WQp = (const char*)Wbf;
  const char* WKp = (const char*)(Wbf + 65536);
  const char* WVp = (const char*)(Wbf + 131072);

  // ---- Q GEMM for this wave's 4 e-tiles: C[p=g*4+rg][e=(w*4+nt)*16+lr] -> mfma16 B-frag ----
  u32x2 qf[4];
  {
    f32x4 acc[4];
#pragma unroll
    for (int nt = 0; nt < 4; ++nt) acc[nt] = z4;
#pragma unroll
    for (int kk = 0; kk < 8; ++kk) {
#pragma unroll
      for (int nt = 0; nt < 4; ++nt) {
        int n = (w * 4 + nt) * 16 + lr;
        FragU bfr;
        bfr.u = *(const u32x4*)(WQp + (size_t)n * 512 + kk * 64 + g * 16);
        acc[nt] = __builtin_amdgcn_mfma_f32_16x16x32_bf16(af[kk].s, bfr.s, acc[nt], 0, 0, 0);
      }
    }
    const float QS = 0.0625f * 1.44269504088896f;  // 1/sqrt(d) * log2(e)
#pragma unroll
    for (int nt = 0; nt < 4; ++nt) {
      float bq = bQ[(w * 4 + nt) * 16 + lr];
      qf[nt].x = pk2((acc[nt][0] + bq) * QS, (acc[nt][1] + bq) * QS);
      qf[nt].y = pk2((acc[nt][2] + bq) * QS, (acc[nt][3] + bq) * QS);
    }
  }

  // ---- phase 1: this wave's 4 K/V chunks -> LDS (per-lane u32x2, same-lane layout) ----
#pragma unroll
  for (int cc = 0; cc < 4; ++cc) {
    int c2 = w * 4 + cc;
    const char* wk = WKp + (size_t)lr * 512 + g * 16 + c2 * 8192;
    const char* wv = WVp + (size_t)lr * 512 + g * 16 + c2 * 8192;

    f32x4 ka0 = z4, ka1 = z4, va0 = z4, va1 = z4;
#pragma unroll
    for (int kk = 0; kk < 8; kk += 2) {
      FragU k0, k1, v0, v1;
      k0.u = *(const u32x4*)(wk + kk * 64);
      k1.u = *(const u32x4*)(wk + kk * 64 + 64);
      v0.u = *(const u32x4*)(wv + kk * 64);
      v1.u = *(const u32x4*)(wv + kk * 64 + 64);
      ka0 = __builtin_amdgcn_mfma_f32_16x16x32_bf16(af[kk].s, k0.s, ka0, 0, 0, 0);
      ka1 = __builtin_amdgcn_mfma_f32_16x16x32_bf16(af[kk + 1].s, k1.s, ka1, 0, 0, 0);
      va0 = __builtin_amdgcn_mfma_f32_16x16x32_bf16(v0.s, af[kk].s, va0, 0, 0, 0);
      va1 = __builtin_amdgcn_mfma_f32_16x16x32_bf16(v1.s, af[kk + 1].s, va1, 0, 0, 0);
    }
    f32x4 ka = ka0 + ka1;
    f32x4 va = va0 + va1;

    float bk = bK[c2 * 16 + lr];
    f32x4 bv4 = *(const f32x4*)(bV + c2 * 16 + g * 4);

    u32x2 kf, vf;
    kf.x = pk2(ka[0] + bk, ka[1] + bk);
    kf.y = pk2(ka[2] + bk, ka[3] + bk);
    vf.x = pk2(va[0] + bv4.x, va[1] + bv4.y);
    vf.y = pk2(va[2] + bv4.z, va[3] + bv4.w);

    *(u32x2*)(&lds[KFO + c2 * 512 + ln * 8]) = kf;
    *(u32x2*)(&lds[VFO + c2 * 512 + ln * 8]) = vf;
  }
  __syncthreads();

  // ---- phase 2: stream all 16 chunks from LDS against this wave's qf ----
  f32x4 accT[4];
  float denp[4];
#pragma unroll
  for (int nt = 0; nt < 4; ++nt) { accT[nt] = z4; denp[nt] = 0.f; }

#pragma unroll
  for (int c2 = 0; c2 < 16; ++c2) {
    u32x2 kf = *(const u32x2*)(&lds[KFO + c2 * 512 + ln * 8]);
    u32x2 vf = *(const u32x2*)(&lds[VFO + c2 * 512 + ln * 8]);
#pragma unroll
    for (int nt = 0; nt < 4; ++nt) {
      f32x4 st = mfma16(kf, qf[nt], z4);
      float p0 = fexp2(st[0]);
      float p1 = fexp2(st[1]);
      float p2 = fexp2(st[2]);
      float p3 = fexp2(st[3]);
      denp[nt] += (p0 + p1) + (p2 + p3);
      u32x2 pB;
      pB.x = pk2(p0, p1);
      pB.y = pk2(p2, p3);
      accT[nt] = mfma16(vf, pB, accT[nt]);
    }
  }

  // ---- den reduce over g-groups; epilogue: accT[nt][rg]=acc^T[p=g*4+rg][e=(w*4+nt)*16+lr] ----
  size_t rowbase = (size_t)b * 4096;
#pragma unroll
  for (int nt = 0; nt < 4; ++nt) {
    float v = denp[nt];
    v += __shfl_xor(v, 16);
    v += __shfl_xor(v, 32);
    float inv = 1.0f / v;
    size_t col = (size_t)((w * 4 + nt) * 16 + lr) * 16 + g * 4;
    f32x4 xr = *(const f32x4*)(x + rowbase + col);
    f32x4 o = accT[nt] * inv + xr;
    *(f32x4*)(out + rowbase + col) = o;
  }
}

extern "C" void kernel_launch(void* const* d_in, const int* in_sizes, int n_in,
                              void* d_out, int out_size, void* d_ws, size_t ws_size,
                              hipStream_t stream) {
  const float* x = (const float*)d_in[0];
  const float* WQ = (const float*)d_in[1];
  const float* bQ = (const float*)d_in[2];
  const float* WK = (const float*)d_in[3];
  const float* bK = (const float*)d_in[4];
  const float* WV = (const float*)d_in[5];
  const float* bV = (const float*)d_in[6];
  const float* gamma = (const float*)d_in[7];
  const float* beta = (const float*)d_in[8];
  float* out = (float*)d_out;
  char* ws = (char*)d_ws;

  float* psum = (float*)(ws);                               // 1 MB
  float* psq = (float*)(ws + (1 << 20));                    // 1 MB
  float* An = (float*)(ws + (2 << 20));                     // 16 KB
  float* Bn = (float*)(ws + (2 << 20) + (16 << 10));        // 16 KB
  unsigned short* Wbf = (unsigned short*)(ws + (3 << 20));  // 384 KB

  hipLaunchKernelGGL(k_wconv, dim3(96), dim3(256), 0, stream, WQ, WK, WV, Wbf);
  hipLaunchKernelGGL(k_stats, dim3(256), dim3(256), 0, stream, x, psum, psq);
  hipLaunchKernelGGL(k_finalize, dim3(16), dim3(256), 0, stream, psum, psq, gamma, beta, An, Bn);
  hipLaunchKernelGGL(k_fused, dim3(4096), dim3(256), 0, stream, x, An, Bn,
                     Wbf, bQ, bK, bV, out);
}

// Round 11
// 181.745 us; speedup vs baseline: 1.6237x; 1.6237x over previous
//
#include <hip/hip_runtime.h>
#include <hip/hip_bf16.h>
#include <stdint.h>

typedef __attribute__((ext_vector_type(8))) short short8;
typedef __attribute__((ext_vector_type(4))) short short4_t;
typedef __attribute__((ext_vector_type(4))) float f32x4;
typedef __attribute__((ext_vector_type(2))) unsigned int u32x2;
typedef __attribute__((ext_vector_type(4))) unsigned int u32x4;

union FragU { u32x4 u; short8 s; };
union Frag2U { u32x2 u; short4_t s; };

__device__ __forceinline__ unsigned short f2bf(float f) {
  union { float f; uint32_t u; } v; v.f = f;
  uint32_t u = v.u;
  return (unsigned short)((u + 0x7FFFu + ((u >> 16) & 1u)) >> 16);
}

__device__ __forceinline__ unsigned pk2(float a, float b) {
  return (unsigned)f2bf(a) | ((unsigned)f2bf(b) << 16);
}

__device__ __forceinline__ void gload_lds16(const void* g, void* l) {
  __builtin_amdgcn_global_load_lds(
      (const __attribute__((address_space(1))) unsigned int*)g,
      (__attribute__((address_space(3))) unsigned int*)l, 16, 0, 0);
}

#if defined(__has_builtin)
#if __has_builtin(__builtin_amdgcn_mfma_f32_16x16x16bf16_1k)
#define HAVE_MFMA16_BUILTIN 1
#endif
#endif

__device__ __forceinline__ f32x4 mfma16(u32x2 a, u32x2 b, f32x4 c) {
#ifdef HAVE_MFMA16_BUILTIN
  Frag2U ua, ub;
  ua.u = a; ub.u = b;
  return __builtin_amdgcn_mfma_f32_16x16x16bf16_1k(ua.s, ub.s, c, 0, 0, 0);
#else
  asm volatile("s_nop 1\n\t"
               "v_mfma_f32_16x16x16_bf16 %0, %1, %2, %0\n\t"
               "s_nop 7\n\t"
               "s_nop 7"
               : "+v"(c) : "v"(a), "v"(b));
  return c;
#endif
}

// ---------------- K0: convert W (f32, [n][k] row-major) -> bf16, same layout ----------------
__global__ __launch_bounds__(256) void k_wconv(const float* __restrict__ WQ,
                                               const float* __restrict__ WK,
                                               const float* __restrict__ WV,
                                               unsigned short* __restrict__ Wbf) {
  int mat = blockIdx.x >> 5;
  int i = blockIdx.x & 31;
  const float* W = (mat == 0) ? WQ : ((mat == 1) ? WK : WV);
  int off = i * 2048 + threadIdx.x * 8;
  f32x4 v0 = *(const f32x4*)(W + off), v1 = *(const f32x4*)(W + off + 4);
  u32x4 pk;
  pk.x = pk2(v0.x, v0.y); pk.y = pk2(v0.z, v0.w);
  pk.z = pk2(v1.x, v1.y); pk.w = pk2(v1.z, v1.w);
  *(u32x4*)(Wbf + (size_t)mat * 65536 + off) = pk;
}

// ---------------- K1a: per-column partial sums over 64-row chunks ----------------
__global__ __launch_bounds__(256) void k_stats(const float* __restrict__ x,
                                               float* __restrict__ psum,
                                               float* __restrict__ psq) {
  int t = threadIdx.x;
  int cb = blockIdx.x & 3;
  int ck = blockIdx.x >> 2;
  int c0 = cb * 1024 + t * 4;
  f32x4 s = {0.f, 0.f, 0.f, 0.f}, q = {0.f, 0.f, 0.f, 0.f};
  const float* base = x + (size_t)ck * 64 * 4096 + c0;
#pragma unroll 4
  for (int r = 0; r < 64; ++r) {
    f32x4 v = *(const f32x4*)(base + (size_t)r * 4096);
    s += v;
    q += v * v;
  }
  *(f32x4*)(psum + (size_t)ck * 4096 + c0) = s;
  *(f32x4*)(psq + (size_t)ck * 4096 + c0) = q;
}

// ---------------- K1b: finalize BN -> fused scale/shift coeffs ----------------
__global__ __launch_bounds__(256) void k_finalize(const float* __restrict__ psum,
                                                  const float* __restrict__ psq,
                                                  const float* __restrict__ gamma,
                                                  const float* __restrict__ beta,
                                                  float* __restrict__ An,
                                                  float* __restrict__ Bn) {
  int c = blockIdx.x * 256 + threadIdx.x;
  float s = 0.f, q = 0.f;
  for (int k = 0; k < 64; ++k) {
    s += psum[k * 4096 + c];
    q += psq[k * 4096 + c];
  }
  float mean = s * (1.0f / 4096.0f);
  float var = q * (1.0f / 4096.0f) - mean * mean;
  float a = gamma[c] * rsqrtf(var + 1e-5f);
  An[c] = a;
  Bn[c] = beta[c] - mean * a;
}

// ---------------- K2: m97-style GEMM: Xn[65536,256] @ Wall[768,256]^T ----------------
// M-tile 128 x N-tile 128, BK=64 (4 K-steps). A: normalized once into 64KB LDS
// (round-3-proven staging). B: per-K-step 16KB via global_load_lds, source
// pre-swizzled (involution), read back with matching XOR. Rolled kb loop.
__global__ __launch_bounds__(256) void k_gemm(
    const float* __restrict__ x, const float* __restrict__ An, const float* __restrict__ Bn,
    const unsigned short* __restrict__ Wbf,
    const float* __restrict__ bQ, const float* __restrict__ bK, const float* __restrict__ bV,
    unsigned short* __restrict__ Qt, unsigned short* __restrict__ Kt,
    unsigned short* __restrict__ Vo) {
  __shared__ char lds[81920];  // Asm 64KB @0, Bsub 16KB @65536
  int t = threadIdx.x;
  int bid = blockIdx.x;
  int nb = bid >> 9;   // 0..5 (N-tile; 512 consecutive blocks share the W panel)
  int mb = bid & 511;  // 0..511 (M-tile)
  int w = t >> 6, ln = t & 63, lr = ln & 15, g = ln >> 4;
  int wm = (w >> 1) * 64, wn = (w & 1) * 64;

  // ---- stage A-tile (128 rows x 256 K), normalize + bf16, swizzled (round-3 pattern) ----
  for (int i = 0; i < 16; ++i) {
    int m = i * 8 + (t >> 5);
    int k0 = (t & 31) * 8;
    size_t r = (size_t)(mb * 128 + m);
    const float* xs = x + r * 256 + k0;
    f32x4 v0 = *(const f32x4*)(xs), v1 = *(const f32x4*)(xs + 4);
    int c = ((int)(r & 15)) * 256 + k0;
    f32x4 a0 = *(const f32x4*)(An + c), a1 = *(const f32x4*)(An + c + 4);
    f32x4 b0 = *(const f32x4*)(Bn + c), b1 = *(const f32x4*)(Bn + c + 4);
    f32x4 n0 = v0 * a0 + b0, n1 = v1 * a1 + b1;
    u32x4 pk;
    pk.x = pk2(n0.x, n0.y); pk.y = pk2(n0.z, n0.w);
    pk.z = pk2(n1.x, n1.y); pk.w = pk2(n1.z, n1.w);
    int off = m * 512 + ((k0 * 2) ^ ((m & 7) << 4));
    *(u32x4*)(&lds[off]) = pk;
  }
  __syncthreads();

  const char* Bbase = (const char*)Wbf + (size_t)(nb * 128) * 512;

  f32x4 acc[4][4];
  f32x4 z4 = {0.f, 0.f, 0.f, 0.f};
#pragma unroll
  for (int a_ = 0; a_ < 4; ++a_)
#pragma unroll
    for (int b_ = 0; b_ < 4; ++b_) acc[a_][b_] = z4;

  for (int kb = 0; kb < 4; ++kb) {
    // stage B sub-tile (128 n-rows x 64 K = 16KB) via global_load_lds,
    // linear LDS dest + inverse-swizzled global source (rule #21 pair)
#pragma unroll
    for (int pc = 0; pc < 4; ++pc) {
      int ob = pc * 4096 + w * 1024;  // wave-uniform dest base
      int o = ob + ln * 16;
      int r = o >> 7;          // n-row 0..127
      int cc = o & 127;        // byte within 128B K-slice
      int sw = cc ^ ((r & 7) << 4);
      gload_lds16(Bbase + (size_t)r * 512 + kb * 128 + sw, &lds[65536 + ob]);
    }
    __syncthreads();  // compiler drains vmcnt before barrier

#pragma unroll
    for (int kk2 = 0; kk2 < 2; ++kk2) {
      int szB = (kk2 * 64 + g * 16) ^ ((lr & 7) << 4);
      int szA = (kb * 128 + kk2 * 64 + g * 16) ^ ((lr & 7) << 4);
      FragU afr[4], bfr[4];
#pragma unroll
      for (int mt = 0; mt < 4; ++mt)
        afr[mt].u = *(const u32x4*)(&lds[(wm + mt * 16 + lr) * 512 + szA]);
#pragma unroll
      for (int nt = 0; nt < 4; ++nt)
        bfr[nt].u = *(const u32x4*)(&lds[65536 + (wn + nt * 16 + lr) * 128 + szB]);
#pragma unroll
      for (int mt = 0; mt < 4; ++mt)
#pragma unroll
        for (int nt = 0; nt < 4; ++nt)
          acc[mt][nt] = __builtin_amdgcn_mfma_f32_16x16x32_bf16(afr[mt].s, bfr[nt].s, acc[mt][nt], 0, 0, 0);
    }
    __syncthreads();  // protect Bsub before next stage
  }

  // ---- epilogue: C layout col(n)=lr, row(m)=g*4+rg ----
  int mat = nb >> 1;
  const float* bias = (mat == 0) ? bQ : ((mat == 1) ? bK : bV);
  float scale = (mat == 0) ? 0.0625f : 1.0f;  // fold 1/sqrt(d)=1/16 into Q
#pragma unroll
  for (int nt = 0; nt < 4; ++nt) {
    int e = (nb & 1) * 128 + wn + nt * 16 + lr;  // local col within the mat
    float bvs = bias[e] * scale;
#pragma unroll
    for (int mt = 0; mt < 4; ++mt) {
      int xrow0 = mb * 128 + wm + mt * 16;  // + g*4+rg; multiple of 16
      if (mat < 2) {
        unsigned short* Out = (mat == 0) ? Qt : Kt;
        int b_ = xrow0 >> 4;  // p = g*4+rg consecutive in [b][e][p]
        u32x2 pk;
        pk.x = pk2(acc[mt][nt][0] * scale + bvs, acc[mt][nt][1] * scale + bvs);
        pk.y = pk2(acc[mt][nt][2] * scale + bvs, acc[mt][nt][3] * scale + bvs);
        *(u32x2*)(Out + (size_t)b_ * 4096 + (size_t)e * 16 + g * 4) = pk;
      } else {
#pragma unroll
        for (int rg = 0; rg < 4; ++rg)
          Vo[(size_t)(xrow0 + g * 4 + rg) * 256 + e] = f2bf(acc[mt][nt][rg] + bvs);
      }
    }
  }
}

// ---------------- K3: per-batch-row attention (verbatim round-5, proven) ----------------
#define LQT 0
#define LKT 8192
#define LVS 16384
#define LTOT 24576

__global__ __launch_bounds__(256, 4) void k_attn(
    const unsigned short* __restrict__ Qtg, const unsigned short* __restrict__ Ktg,
    const unsigned short* __restrict__ Vg, const float* __restrict__ x,
    float* __restrict__ out) {
  __shared__ char lds[LTOT];
  int b = blockIdx.x;
  int t = threadIdx.x;
  int w = t >> 6, ln = t & 63, lr = ln & 15, g = ln >> 4;

  for (int i = w; i < 24; i += 4) {
    const unsigned short* srcmat;
    unsigned srcbyte;
    int region;
    if (i < 8) {
      srcmat = Qtg;
      srcbyte = (unsigned)b * 8192 + i * 1024 + ln * 16;
      region = LQT + i * 1024;
    } else if (i < 16) {
      int ii = i - 8;
      srcmat = Ktg;
      srcbyte = (unsigned)b * 8192 + ii * 1024 + ln * 16;
      region = LKT + ii * 1024;
    } else {
      int ii = i - 16;
      srcmat = Vg;
      int d = ii * 1024 + ln * 16;
      int p = d >> 9;
      int cc = d & 511;
      srcbyte = (unsigned)b * 8192 + p * 512 + (unsigned)(cc ^ ((p & 7) << 4));
      region = LVS + ii * 1024;
    }
    gload_lds16((const char*)srcmat + srcbyte, &lds[region]);
  }
  __syncthreads();

  u32x2 qf[4];
#pragma unroll
  for (int nt = 0; nt < 4; ++nt)
    qf[nt] = *(const u32x2*)(&lds[LQT + (w * 64 + nt * 16 + lr) * 32 + g * 8]);

  f32x4 accT[4];
  float denp[4];
  f32x4 z4 = {0.f, 0.f, 0.f, 0.f};
#pragma unroll
  for (int nt = 0; nt < 4; ++nt) { accT[nt] = z4; denp[nt] = 0.f; }

  for (int c = 0; c < 8; ++c) {
#pragma unroll
    for (int mt_ = 0; mt_ < 2; ++mt_) {
      u32x2 kf = *(const u32x2*)(&lds[LKT + (c * 32 + mt_ * 16 + lr) * 32 + g * 8]);

      f32x4 st[4];
#pragma unroll
      for (int nt = 0; nt < 4; ++nt)
        st[nt] = mfma16(kf, qf[nt], z4);

      u32x2 vf = *(const u32x2*)(
          &lds[LVS + lr * 512 + ((c * 64 + mt_ * 32 + g * 8) ^ ((lr & 7) << 4))]);

#pragma unroll
      for (int nt = 0; nt < 4; ++nt) {
        float e0 = __expf(st[nt].x);
        float e1 = __expf(st[nt].y);
        float e2 = __expf(st[nt].z);
        float e3 = __expf(st[nt].w);
        denp[nt] += (e0 + e1) + (e2 + e3);
        u32x2 pB;
        pB.x = pk2(e0, e1);
        pB.y = pk2(e2, e3);
        accT[nt] = mfma16(vf, pB, accT[nt]);
      }
    }
  }

#pragma unroll
  for (int nt = 0; nt < 4; ++nt) {
    float v = denp[nt];
    v += __shfl_xor(v, 16);
    v += __shfl_xor(v, 32);
    denp[nt] = v;
  }

  size_t rowbase = (size_t)b * 4096;
#pragma unroll
  for (int nt = 0; nt < 4; ++nt) {
    int e = w * 64 + nt * 16 + lr;
    size_t col = (size_t)e * 16 + g * 4;
    float inv = 1.0f / denp[nt];
    f32x4 xr = *(const f32x4*)(x + rowbase + col);
    f32x4 o = accT[nt] * inv + xr;
    *(f32x4*)(out + rowbase + col) = o;
  }
}

extern "C" void kernel_launch(void* const* d_in, const int* in_sizes, int n_in,
                              void* d_out, int out_size, void* d_ws, size_t ws_size,
                              hipStream_t stream) {
  const float* x = (const float*)d_in[0];
  const float* WQ = (const float*)d_in[1];
  const float* bQ = (const float*)d_in[2];
  const float* WK = (const float*)d_in[3];
  const float* bK = (const float*)d_in[4];
  const float* WV = (const float*)d_in[5];
  const float* bV = (const float*)d_in[6];
  const float* gamma = (const float*)d_in[7];
  const float* beta = (const float*)d_in[8];
  float* out = (float*)d_out;
  char* ws = (char*)d_ws;

  float* psum = (float*)(ws);                                  // 1 MB
  float* psq = (float*)(ws + (1 << 20));                       // 1 MB
  float* An = (float*)(ws + (2 << 20));                        // 16 KB
  float* Bn = (float*)(ws + (2 << 20) + (16 << 10));           // 16 KB
  unsigned short* Wbf = (unsigned short*)(ws + (3 << 20));     // 384 KB
  unsigned short* Qt = (unsigned short*)(ws + (size_t)(4 << 20));                 // 32 MB [b][e][p]
  unsigned short* Kt = (unsigned short*)(ws + (size_t)(4 << 20) + (32u << 20));   // 32 MB [b][f][p]
  unsigned short* Vo = (unsigned short*)(ws + (size_t)(4 << 20) + (64u << 20));   // 32 MB [xrow][f]

  hipLaunchKernelGGL(k_wconv, dim3(96), dim3(256), 0, stream, WQ, WK, WV, Wbf);
  hipLaunchKernelGGL(k_stats, dim3(256), dim3(256), 0, stream, x, psum, psq);
  hipLaunchKernelGGL(k_finalize, dim3(16), dim3(256), 0, stream, psum, psq, gamma, beta, An, Bn);
  hipLaunchKernelGGL(k_gemm, dim3(3072), dim3(256), 0, stream, x, An, Bn,
                     Wbf, bQ, bK, bV, Qt, Kt, Vo);
  hipLaunchKernelGGL(k_attn, dim3(4096), dim3(256), 0, stream, Qt, Kt, Vo, x, out);
}